// Round 7
// baseline (1059.600 us; speedup 1.0000x reference)
//
#include <hip/hip_runtime.h>
#include <math.h>

typedef float f32x4 __attribute__((ext_vector_type(4)));

#define FDIM 128
#define NRBF 20
#define RCUT 5.0f
#define PI_F 3.14159265358979323846f

// ---------------------------------------------------------------------------
// Kernel 1: per-node transform
//   phi_node[n,:] = silu(s[n,:] @ W1 + b1) @ W2 + b2        (N x 384, f32)
// Block = 256 threads, BM = 64 rows/block.
// LDS: AB (64x128 f32, 32KB; holds S tile, then reused for H tile)
//    + WB (64x128 f32, 32KB; staged 64-k-row chunks of W1/W2)  = 64KB
//    -> 2 blocks/CU (8 waves/CU, 2 waves/SIMD).
// Micro-tile: thread (rg,ct) = (tid>>5, tid&31) computes rows rg+8i (i<8),
// cols ct*4..ct*4+3. Per k-quad: 12 ds_read_b128, 128 FMAs.
// ---------------------------------------------------------------------------
__launch_bounds__(256, 2)
__global__ void node_phi_kernel(const float* __restrict__ s,
                                const float* __restrict__ W1,
                                const float* __restrict__ b1,
                                const float* __restrict__ W2,
                                const float* __restrict__ b2,
                                float* __restrict__ phi,
                                int N) {
    __shared__ f32x4 AB[64 * 32];    // S tile, then H tile   [row][kq]
    __shared__ f32x4 WB[64 * 32];    // weight chunk          [k-row][cq]

    const int tid = threadIdx.x;
    const int ct  = tid & 31;        // col quad 0..31
    const int rg  = tid >> 5;        // row group 0..7
    const int base = blockIdx.x * 64;

    // ---- load s tile (guard rows) ----
    {
        const f32x4* sg = (const f32x4*)s;
        #pragma unroll
        for (int i = 0; i < 8; ++i) {
            int fidx = tid + 256 * i;           // 2048 float4 total
            int row  = fidx >> 5;
            f32x4 val = {0.f, 0.f, 0.f, 0.f};
            if (base + row < N) val = sg[(size_t)(base + row) * 32 + (fidx & 31)];
            AB[fidx] = val;
        }
    }

    // ---- stage 1: h = silu(s @ W1 + b1), W1 staged in two 64-row halves ----
    f32x4 acc[8];
    #pragma unroll
    for (int i = 0; i < 8; ++i) acc[i] = (f32x4){0.f, 0.f, 0.f, 0.f};

    for (int h = 0; h < 2; ++h) {
        __syncthreads();   // prior WB readers done (h=1); harmless at h=0
        const f32x4* wg = (const f32x4*)W1 + h * 64 * 32;
        #pragma unroll
        for (int i = 0; i < 8; ++i) {
            int fidx = tid + 256 * i;           // 2048 float4
            WB[fidx] = wg[fidx];
        }
        __syncthreads();   // WB ready (and S tile ready at h=0)

        #pragma unroll 4
        for (int kq = 0; kq < 16; ++kq) {
            f32x4 w0 = WB[(4 * kq + 0) * 32 + ct];
            f32x4 w1 = WB[(4 * kq + 1) * 32 + ct];
            f32x4 w2 = WB[(4 * kq + 2) * 32 + ct];
            f32x4 w3 = WB[(4 * kq + 3) * 32 + ct];
            #pragma unroll
            for (int i = 0; i < 8; ++i) {
                f32x4 sv = AB[(rg + 8 * i) * 32 + (h * 16 + kq)];
                acc[i] += sv.x * w0;
                acc[i] += sv.y * w1;
                acc[i] += sv.z * w2;
                acc[i] += sv.w * w3;
            }
        }
    }

    // ---- silu, write H over the S tile ----
    __syncthreads();   // all stage-1 reads of AB done
    {
        f32x4 bb = ((const f32x4*)b1)[ct];
        #pragma unroll
        for (int i = 0; i < 8; ++i) {
            f32x4 x = acc[i] + bb;
            f32x4 hv;
            hv.x = x.x / (1.f + __expf(-x.x));
            hv.y = x.y / (1.f + __expf(-x.y));
            hv.z = x.z / (1.f + __expf(-x.z));
            hv.w = x.w / (1.f + __expf(-x.w));
            AB[(rg + 8 * i) * 32 + ct] = hv;   // covers all 64 rows x 32 quads
        }
    }
    __syncthreads();   // H visible

    // ---- stage 2: phi = h @ W2 + b2, 3 col chunks x 2 k-halves ----
    const f32x4* w2g = (const f32x4*)W2;   // W2 row stride = 96 float4
    f32x4* phig = (f32x4*)phi;             // phi row stride = 96 float4
    for (int cc = 0; cc < 3; ++cc) {
        f32x4 acc2[8];
        #pragma unroll
        for (int i = 0; i < 8; ++i) acc2[i] = (f32x4){0.f, 0.f, 0.f, 0.f};

        for (int h = 0; h < 2; ++h) {
            __syncthreads();   // prior WB readers done
            #pragma unroll
            for (int i = 0; i < 8; ++i) {
                int fidx = tid + 256 * i;
                int row  = fidx >> 5;
                WB[fidx] = w2g[(size_t)(h * 64 + row) * 96 + cc * 32 + (fidx & 31)];
            }
            __syncthreads();

            #pragma unroll 4
            for (int kq = 0; kq < 16; ++kq) {
                f32x4 w0 = WB[(4 * kq + 0) * 32 + ct];
                f32x4 w1 = WB[(4 * kq + 1) * 32 + ct];
                f32x4 w2v = WB[(4 * kq + 2) * 32 + ct];
                f32x4 w3 = WB[(4 * kq + 3) * 32 + ct];
                #pragma unroll
                for (int i = 0; i < 8; ++i) {
                    f32x4 hv = AB[(rg + 8 * i) * 32 + (h * 16 + kq)];
                    acc2[i] += hv.x * w0;
                    acc2[i] += hv.y * w1;
                    acc2[i] += hv.z * w2v;
                    acc2[i] += hv.w * w3;
                }
            }
        }

        f32x4 bb2 = ((const f32x4*)b2)[cc * 32 + ct];
        #pragma unroll
        for (int i = 0; i < 8; ++i) {
            int row = rg + 8 * i;
            if (base + row < N)
                phig[(size_t)(base + row) * 96 + cc * 32 + ct] = acc2[i] + bb2;
        }
    }
}

// ---------------------------------------------------------------------------
// Kernel 2: per-edge message + scatter — barrier-free, wave-synchronous.
// One wave = one (edge, feature-half) item: h = witem&1 (invariant under the
// even grid-stride), f = h*64 + lane. No LDS, no __syncthreads.
// Every lane loads r_ij (uniform addr -> one coalesced request) and derives
// d/dir/fcut locally; only the 20 rbf values are shared, via __shfl.
// Each lane keeps its 3 Wr columns (60 f32) in registers across all edges.
// ---------------------------------------------------------------------------
__launch_bounds__(256, 4)
__global__ void edge_kernel(const float* __restrict__ r_ij,
                            const int* __restrict__ src,
                            const int* __restrict__ dst,
                            const float* __restrict__ Wr,
                            const float* __restrict__ br,
                            const float* __restrict__ phi,
                            const float* __restrict__ v,
                            float* __restrict__ out_v,
                            float* __restrict__ out_s,
                            int E) {
    const int tid   = threadIdx.x;
    const int lane  = tid & 63;
    const int wid   = tid >> 6;                 // wave in block, 0..3
    const int witem = blockIdx.x * 4 + wid;     // global wave-item
    const int h     = witem & 1;                // feature half, fixed per wave
    const int f     = h * 64 + lane;            // this lane's feature, fixed
    const int estep = gridDim.x * 2;            // edge stride (items/2)

    // hoist this lane's Wr columns + biases (constant over edges)
    float wr_a[NRBF], wr_b[NRBF], wr_c[NRBF];
    #pragma unroll
    for (int k = 0; k < NRBF; ++k) {
        wr_a[k] = Wr[k * 384 + f];
        wr_b[k] = Wr[k * 384 + 128 + f];
        wr_c[k] = Wr[k * 384 + 256 + f];
    }
    const float br_a = br[f];
    const float br_b = br[128 + f];
    const float br_c = br[256 + f];

    for (int e = witem >> 1; e < E; e += estep) {
        const float x = r_ij[e * 3 + 0];
        const float y = r_ij[e * 3 + 1];
        const float z = r_ij[e * 3 + 2];
        const float d = sqrtf(x * x + y * y + z * z);
        const float inv_d = 1.0f / d;

        // lanes 0..19 compute the 20 rbf values; shared below via shfl
        float rbf_reg = 0.f;
        if (lane < NRBF) {
            float arg = (float)(lane + 1) * (PI_F / RCUT) * d;
            rbf_reg = sinf(arg) * inv_d;
        }
        // fcut + dir: every lane has d locally — pure per-lane arithmetic
        const float fc = (d < RCUT) ? 0.5f * (cosf(PI_F * d * (1.0f / RCUT)) + 1.f) : 0.f;
        const float dx = x * inv_d, dy = y * inv_d, dz = z * inv_d;

        float wa = br_a, wb = br_b, wc = br_c;
        #pragma unroll
        for (int k = 0; k < NRBF; ++k) {
            const float r = __shfl(rbf_reg, k);
            wa += r * wr_a[k];
            wb += r * wr_b[k];
            wc += r * wr_c[k];
        }
        wa *= fc; wb *= fc; wc *= fc;

        const int sn = src[e];
        const int dn = dst[e];
        const size_t sb = (size_t)sn * 384;
        const float a = wa * phi[sb + f];
        const float b = wb * phi[sb + 128 + f];
        const float c = wc * phi[sb + 256 + f];

        atomicAdd(&out_s[(size_t)dn * 128 + f], b);

        const float vx = v[sb + f];
        const float vy = v[sb + 128 + f];
        const float vz = v[sb + 256 + f];
        const size_t ob = (size_t)dn * 384;
        atomicAdd(&out_v[ob + f],       a * vx + c * dx);
        atomicAdd(&out_v[ob + 128 + f], a * vy + c * dy);
        atomicAdd(&out_v[ob + 256 + f], a * vz + c * dz);
    }
}

// ---------------------------------------------------------------------------
extern "C" void kernel_launch(void* const* d_in, const int* in_sizes, int n_in,
                              void* d_out, int out_size, void* d_ws, size_t ws_size,
                              hipStream_t stream) {
    const float* s    = (const float*)d_in[0];
    const float* v    = (const float*)d_in[1];
    const float* r_ij = (const float*)d_in[2];
    const int*   src  = (const int*)d_in[3];
    const int*   dst  = (const int*)d_in[4];
    const float* W1   = (const float*)d_in[5];
    const float* b1   = (const float*)d_in[6];
    const float* W2   = (const float*)d_in[7];
    const float* b2   = (const float*)d_in[8];
    const float* Wr   = (const float*)d_in[9];
    const float* br   = (const float*)d_in[10];

    const int N = in_sizes[0] / FDIM;   // 50000
    const int E = in_sizes[3];          // 400000

    float* phi = (float*)d_ws;                       // N x 384 f32 (76.8 MB)
    float* out_v = (float*)d_out;                    // N x 3 x 128
    float* out_s = (float*)d_out + (size_t)N * 384;  // N x 128

    // zero the atomic accumulation targets (poisoned with 0xAA)
    hipMemsetAsync(d_out, 0, (size_t)out_size * sizeof(float), stream);

    // per-node phi
    dim3 g1((N + 63) / 64);
    node_phi_kernel<<<g1, 256, 0, stream>>>(s, W1, b1, W2, b2, phi, N);

    // per-edge messages + scatter (barrier-free wave-synchronous)
    dim3 g2(2048);
    edge_kernel<<<g2, 256, 0, stream>>>(r_ij, src, dst, Wr, br, phi, v,
                                        out_v, out_s, E);
}

// Round 11
// 798.190 us; speedup vs baseline: 1.3275x; 1.3275x over previous
//
#include <hip/hip_runtime.h>
#include <math.h>

typedef float f32x4 __attribute__((ext_vector_type(4)));

#define FDIM 128
#define NRBF 20
#define RCUT 5.0f
#define PI_F 3.14159265358979323846f

// ---------------------------------------------------------------------------
// Kernel 1: per-node transform   phi[n,:] = silu(s[n,:]@W1+b1)@W2+b2
// v2: W1/W2 read directly from global (256KB total, L2-resident; lanes share
// addresses 2-way -> broadcast-coalesced). LDS = 32KB (S tile, reused for H).
// 3 barriers total (was 18). 4-5 blocks/CU (was 2).
// ---------------------------------------------------------------------------
__launch_bounds__(256, 4)
__global__ void node_phi_kernel(const float* __restrict__ s,
                                const float* __restrict__ W1,
                                const float* __restrict__ b1,
                                const float* __restrict__ W2,
                                const float* __restrict__ b2,
                                float* __restrict__ phi,
                                int N) {
    __shared__ f32x4 AB[64 * 32];    // S tile, then H tile   [row][kq]

    const int tid = threadIdx.x;
    const int ct  = tid & 31;        // col quad 0..31
    const int rg  = tid >> 5;        // row group 0..7
    const int base = blockIdx.x * 64;

    // ---- load s tile (guard rows) ----
    {
        const f32x4* sg = (const f32x4*)s;
        #pragma unroll
        for (int i = 0; i < 8; ++i) {
            int fidx = tid + 256 * i;           // 2048 float4 total
            int row  = fidx >> 5;
            f32x4 val = {0.f, 0.f, 0.f, 0.f};
            if (base + row < N) val = sg[(size_t)(base + row) * 32 + (fidx & 31)];
            AB[fidx] = val;
        }
    }
    __syncthreads();

    // ---- stage 1: h = silu(s @ W1 + b1), W1 from global ----
    const f32x4* w1g = (const f32x4*)W1;       // row stride 32 f32x4
    f32x4 acc[8];
    #pragma unroll
    for (int i = 0; i < 8; ++i) acc[i] = (f32x4){0.f, 0.f, 0.f, 0.f};

    #pragma unroll 4
    for (int kq = 0; kq < 32; ++kq) {
        f32x4 w0 = w1g[(4 * kq + 0) * 32 + ct];
        f32x4 w1 = w1g[(4 * kq + 1) * 32 + ct];
        f32x4 w2 = w1g[(4 * kq + 2) * 32 + ct];
        f32x4 w3 = w1g[(4 * kq + 3) * 32 + ct];
        #pragma unroll
        for (int i = 0; i < 8; ++i) {
            f32x4 sv = AB[(rg + 8 * i) * 32 + kq];
            acc[i] += sv.x * w0;
            acc[i] += sv.y * w1;
            acc[i] += sv.z * w2;
            acc[i] += sv.w * w3;
        }
    }

    __syncthreads();   // all stage-1 reads of AB done
    {
        f32x4 bb = ((const f32x4*)b1)[ct];
        #pragma unroll
        for (int i = 0; i < 8; ++i) {
            f32x4 x = acc[i] + bb;
            f32x4 hv;
            hv.x = x.x / (1.f + __expf(-x.x));
            hv.y = x.y / (1.f + __expf(-x.y));
            hv.z = x.z / (1.f + __expf(-x.z));
            hv.w = x.w / (1.f + __expf(-x.w));
            AB[(rg + 8 * i) * 32 + ct] = hv;
        }
    }
    __syncthreads();   // H visible

    // ---- stage 2: phi = h @ W2 + b2, W2 from global, 3 col chunks ----
    const f32x4* w2g = (const f32x4*)W2;   // row stride = 96 f32x4
    f32x4* phig = (f32x4*)phi;             // row stride = 96 f32x4
    for (int cc = 0; cc < 3; ++cc) {
        f32x4 acc2[8];
        #pragma unroll
        for (int i = 0; i < 8; ++i) acc2[i] = (f32x4){0.f, 0.f, 0.f, 0.f};

        #pragma unroll 4
        for (int kq = 0; kq < 32; ++kq) {
            f32x4 w0 = w2g[(size_t)(4 * kq + 0) * 96 + cc * 32 + ct];
            f32x4 w1 = w2g[(size_t)(4 * kq + 1) * 96 + cc * 32 + ct];
            f32x4 w2v = w2g[(size_t)(4 * kq + 2) * 96 + cc * 32 + ct];
            f32x4 w3 = w2g[(size_t)(4 * kq + 3) * 96 + cc * 32 + ct];
            #pragma unroll
            for (int i = 0; i < 8; ++i) {
                f32x4 hv = AB[(rg + 8 * i) * 32 + kq];
                acc2[i] += hv.x * w0;
                acc2[i] += hv.y * w1;
                acc2[i] += hv.z * w2v;
                acc2[i] += hv.w * w3;
            }
        }

        f32x4 bb2 = ((const f32x4*)b2)[cc * 32 + ct];
        #pragma unroll
        for (int i = 0; i < 8; ++i) {
            int row = rg + 8 * i;
            if (base + row < N)
                phig[(size_t)(base + row) * 96 + cc * 32 + ct] = acc2[i] + bb2;
        }
    }
}

// ---------------------------------------------------------------------------
// Sort phase: counting sort of edges by dst.
// ---------------------------------------------------------------------------
__global__ void hist_kernel(const int* __restrict__ dst, int* __restrict__ counts, int E) {
    int e = blockIdx.x * 256 + threadIdx.x;
    if (e < E) atomicAdd(&counts[dst[e]], 1);
}

// Single-block exclusive scan over N counts -> offsets[N+1]; also rewrites
// counts_cursor[i] = exclusive prefix (the scatter cursor). Wave-shfl scan +
// tiny LDS combine; ~200 chunk iterations.
__global__ void scan_kernel(int* __restrict__ counts_cursor,
                            int* __restrict__ offsets, int N) {
    __shared__ int wsum[4];
    __shared__ int carry_sh;
    __shared__ int ctot_sh;
    const int tid  = threadIdx.x;
    const int lane = tid & 63;
    const int w    = tid >> 6;
    if (tid == 0) carry_sh = 0;
    __syncthreads();
    for (int base = 0; base < N; base += 256) {
        const int i = base + tid;
        const int x = (i < N) ? counts_cursor[i] : 0;
        int ix = x;
        #pragma unroll
        for (int off = 1; off < 64; off <<= 1) {
            int y = __shfl_up(ix, off);
            if (lane >= off) ix += y;
        }
        if (lane == 63) wsum[w] = ix;
        __syncthreads();
        if (tid == 0) {
            int a = 0;
            #pragma unroll
            for (int j = 0; j < 4; ++j) { int t = wsum[j]; wsum[j] = a; a += t; }
            ctot_sh = a;
        }
        __syncthreads();
        const int excl = ix - x + wsum[w] + carry_sh;
        if (i < N) { offsets[i] = excl; counts_cursor[i] = excl; }
        __syncthreads();                 // reads of carry_sh / wsum done
        if (tid == 0) carry_sh += ctot_sh;
        __syncthreads();                 // update visible; wsum reusable
    }
    if (tid == 0) offsets[N] = carry_sh;
}

__global__ void scatter_kernel(const int* __restrict__ dst, int* __restrict__ cursor,
                               int* __restrict__ sorted, int E) {
    int e = blockIdx.x * 256 + threadIdx.x;
    if (e < E) {
        int p = atomicAdd(&cursor[dst[e]], 1);
        sorted[p] = e;
    }
}

// ---------------------------------------------------------------------------
// Kernel 5: dst-grouped gather-accumulate. One wave = one (node, feature-half)
// item; h = witem&1 invariant (item stride even), f = h*64+lane fixed -> 60
// Wr registers hoisted. Per 64-edge chunk, lane k stages edge k's metadata
// (eid, src, r_ij) -> inner loop is shfl-fed, gathers issue immediately.
// Accumulate in 4 registers; ONE coalesced store per output element; no
// atomics; every output element written (no memset needed).
// ---------------------------------------------------------------------------
__launch_bounds__(256, 4)
__global__ void edge_accum_kernel(const float* __restrict__ r_ij,
                                  const int* __restrict__ src,
                                  const int* __restrict__ offsets,
                                  const int* __restrict__ sorted,
                                  const float* __restrict__ Wr,
                                  const float* __restrict__ br,
                                  const float* __restrict__ phi,
                                  const float* __restrict__ v,
                                  float* __restrict__ out_v,
                                  float* __restrict__ out_s,
                                  int N) {
    const int tid    = threadIdx.x;
    const int lane   = tid & 63;
    const int wid    = tid >> 6;
    const int witem0 = blockIdx.x * 4 + wid;
    const int istep  = gridDim.x * 4;          // even -> h invariant
    const int h      = witem0 & 1;
    const int f      = h * 64 + lane;

    float wr_a[NRBF], wr_b[NRBF], wr_c[NRBF];
    #pragma unroll
    for (int k = 0; k < NRBF; ++k) {
        wr_a[k] = Wr[k * 384 + f];
        wr_b[k] = Wr[k * 384 + 128 + f];
        wr_c[k] = Wr[k * 384 + 256 + f];
    }
    const float br_a = br[f];
    const float br_b = br[128 + f];
    const float br_c = br[256 + f];

    for (int witem = witem0; witem < 2 * N; witem += istep) {
        const int n   = witem >> 1;
        const int beg = offsets[n];
        const int end = offsets[n + 1];

        float acc_s = 0.f, acc_x = 0.f, acc_y = 0.f, acc_z = 0.f;

        for (int kb = beg; kb < end; kb += 64) {
            const int kk = kb + lane;
            int   sn = 0;
            float rx = 0.f, ry = 0.f, rz = 0.f;
            if (kk < end) {
                const int eid = sorted[kk];
                sn = src[eid];
                rx = r_ij[eid * 3 + 0];
                ry = r_ij[eid * 3 + 1];
                rz = r_ij[eid * 3 + 2];
            }
            const int cnt = min(64, end - kb);
            for (int j = 0; j < cnt; ++j) {
                const int   snj = __shfl(sn, j);
                const float x   = __shfl(rx, j);
                const float y   = __shfl(ry, j);
                const float z   = __shfl(rz, j);

                const size_t sb = (size_t)snj * 384;
                const float pa = phi[sb + f];
                const float pb = phi[sb + 128 + f];
                const float pc = phi[sb + 256 + f];
                const float vx = v[sb + f];
                const float vy = v[sb + 128 + f];
                const float vz = v[sb + 256 + f];

                const float d     = sqrtf(x * x + y * y + z * z);
                const float inv_d = 1.0f / d;
                float rbf_reg = 0.f;
                if (lane < NRBF)
                    rbf_reg = sinf((float)(lane + 1) * (PI_F / RCUT) * d) * inv_d;
                const float fc = (d < RCUT)
                                 ? 0.5f * (cosf(PI_F * (1.0f / RCUT) * d) + 1.f) : 0.f;

                float wa = br_a, wb = br_b, wc = br_c;
                #pragma unroll
                for (int k = 0; k < NRBF; ++k) {
                    const float r = __shfl(rbf_reg, k);
                    wa += r * wr_a[k];
                    wb += r * wr_b[k];
                    wc += r * wr_c[k];
                }
                wa *= fc; wb *= fc; wc *= fc;

                const float a = wa * pa;
                const float b = wb * pb;
                const float c = wc * pc;

                acc_s += b;
                acc_x += a * vx + c * (x * inv_d);
                acc_y += a * vy + c * (y * inv_d);
                acc_z += a * vz + c * (z * inv_d);
            }
        }

        out_s[(size_t)n * 128 + f] = acc_s;
        const size_t ob = (size_t)n * 384;
        out_v[ob + f]        = acc_x;
        out_v[ob + 128 + f]  = acc_y;
        out_v[ob + 256 + f]  = acc_z;
    }
}

// ---------------------------------------------------------------------------
extern "C" void kernel_launch(void* const* d_in, const int* in_sizes, int n_in,
                              void* d_out, int out_size, void* d_ws, size_t ws_size,
                              hipStream_t stream) {
    const float* s    = (const float*)d_in[0];
    const float* v    = (const float*)d_in[1];
    const float* r_ij = (const float*)d_in[2];
    const int*   src  = (const int*)d_in[3];
    const int*   dst  = (const int*)d_in[4];
    const float* W1   = (const float*)d_in[5];
    const float* b1   = (const float*)d_in[6];
    const float* W2   = (const float*)d_in[7];
    const float* b2   = (const float*)d_in[8];
    const float* Wr   = (const float*)d_in[9];
    const float* br   = (const float*)d_in[10];

    const int N = in_sizes[0] / FDIM;   // 50000
    const int E = in_sizes[3];          // 400000

    // workspace layout: phi (N*384 f32) | offsets (N+1) | cursor (N) | sorted (E)
    float* phi     = (float*)d_ws;
    int*   offsets = (int*)(phi + (size_t)N * 384);
    int*   cursor  = offsets + (N + 1);         // doubles as counts
    int*   sorted  = cursor + N;

    float* out_v = (float*)d_out;                    // N x 3 x 128
    float* out_s = (float*)d_out + (size_t)N * 384;  // N x 128

    // zero histogram (cursor doubles as counts)
    hipMemsetAsync(cursor, 0, (size_t)N * sizeof(int), stream);

    hist_kernel<<<dim3((E + 255) / 256), 256, 0, stream>>>(dst, cursor, E);

    dim3 g1((N + 63) / 64);
    node_phi_kernel<<<g1, 256, 0, stream>>>(s, W1, b1, W2, b2, phi, N);

    scan_kernel<<<dim3(1), 256, 0, stream>>>(cursor, offsets, N);

    scatter_kernel<<<dim3((E + 255) / 256), 256, 0, stream>>>(dst, cursor, sorted, E);

    edge_accum_kernel<<<dim3(2048), 256, 0, stream>>>(r_ij, src, offsets, sorted,
                                                      Wr, br, phi, v,
                                                      out_v, out_s, N);
}

// Round 13
// 584.223 us; speedup vs baseline: 1.8137x; 1.3662x over previous
//
#include <hip/hip_runtime.h>
#include <math.h>

typedef float f32x4 __attribute__((ext_vector_type(4)));

#define FDIM 128
#define NRBF 20
#define RCUT 5.0f
#define PI_F 3.14159265358979323846f

// ---------------------------------------------------------------------------
// Kernel 1: per-node transform   phi[n,:] = silu(s[n,:]@W1+b1)@W2+b2
// W1/W2 read directly from global (256KB, L2-resident); LDS 32KB; 3 barriers.
// ---------------------------------------------------------------------------
__launch_bounds__(256, 4)
__global__ void node_phi_kernel(const float* __restrict__ s,
                                const float* __restrict__ W1,
                                const float* __restrict__ b1,
                                const float* __restrict__ W2,
                                const float* __restrict__ b2,
                                float* __restrict__ phi,
                                int N) {
    __shared__ f32x4 AB[64 * 32];    // S tile, then H tile   [row][kq]

    const int tid = threadIdx.x;
    const int ct  = tid & 31;        // col quad 0..31
    const int rg  = tid >> 5;        // row group 0..7
    const int base = blockIdx.x * 64;

    {
        const f32x4* sg = (const f32x4*)s;
        #pragma unroll
        for (int i = 0; i < 8; ++i) {
            int fidx = tid + 256 * i;
            int row  = fidx >> 5;
            f32x4 val = {0.f, 0.f, 0.f, 0.f};
            if (base + row < N) val = sg[(size_t)(base + row) * 32 + (fidx & 31)];
            AB[fidx] = val;
        }
    }
    __syncthreads();

    const f32x4* w1g = (const f32x4*)W1;
    f32x4 acc[8];
    #pragma unroll
    for (int i = 0; i < 8; ++i) acc[i] = (f32x4){0.f, 0.f, 0.f, 0.f};

    #pragma unroll 4
    for (int kq = 0; kq < 32; ++kq) {
        f32x4 w0 = w1g[(4 * kq + 0) * 32 + ct];
        f32x4 w1 = w1g[(4 * kq + 1) * 32 + ct];
        f32x4 w2 = w1g[(4 * kq + 2) * 32 + ct];
        f32x4 w3 = w1g[(4 * kq + 3) * 32 + ct];
        #pragma unroll
        for (int i = 0; i < 8; ++i) {
            f32x4 sv = AB[(rg + 8 * i) * 32 + kq];
            acc[i] += sv.x * w0;
            acc[i] += sv.y * w1;
            acc[i] += sv.z * w2;
            acc[i] += sv.w * w3;
        }
    }

    __syncthreads();
    {
        f32x4 bb = ((const f32x4*)b1)[ct];
        #pragma unroll
        for (int i = 0; i < 8; ++i) {
            f32x4 x = acc[i] + bb;
            f32x4 hv;
            hv.x = x.x / (1.f + __expf(-x.x));
            hv.y = x.y / (1.f + __expf(-x.y));
            hv.z = x.z / (1.f + __expf(-x.z));
            hv.w = x.w / (1.f + __expf(-x.w));
            AB[(rg + 8 * i) * 32 + ct] = hv;
        }
    }
    __syncthreads();

    const f32x4* w2g = (const f32x4*)W2;
    f32x4* phig = (f32x4*)phi;
    for (int cc = 0; cc < 3; ++cc) {
        f32x4 acc2[8];
        #pragma unroll
        for (int i = 0; i < 8; ++i) acc2[i] = (f32x4){0.f, 0.f, 0.f, 0.f};

        #pragma unroll 4
        for (int kq = 0; kq < 32; ++kq) {
            f32x4 w0 = w2g[(size_t)(4 * kq + 0) * 96 + cc * 32 + ct];
            f32x4 w1 = w2g[(size_t)(4 * kq + 1) * 96 + cc * 32 + ct];
            f32x4 w2v = w2g[(size_t)(4 * kq + 2) * 96 + cc * 32 + ct];
            f32x4 w3 = w2g[(size_t)(4 * kq + 3) * 96 + cc * 32 + ct];
            #pragma unroll
            for (int i = 0; i < 8; ++i) {
                f32x4 hv = AB[(rg + 8 * i) * 32 + kq];
                acc2[i] += hv.x * w0;
                acc2[i] += hv.y * w1;
                acc2[i] += hv.z * w2v;
                acc2[i] += hv.w * w3;
            }
        }

        f32x4 bb2 = ((const f32x4*)b2)[cc * 32 + ct];
        #pragma unroll
        for (int i = 0; i < 8; ++i) {
            int row = rg + 8 * i;
            if (base + row < N)
                phig[(size_t)(base + row) * 96 + cc * 32 + ct] = acc2[i] + bb2;
        }
    }
}

// ---------------------------------------------------------------------------
// Counting sort by dst: hist -> two-level parallel scan -> scatter.
// (v2: the old single-block serial scan was ~196 latency-chained iterations.)
// ---------------------------------------------------------------------------
__global__ void hist_kernel(const int* __restrict__ dst, int* __restrict__ counts, int E) {
    int e = blockIdx.x * 256 + threadIdx.x;
    if (e < E) atomicAdd(&counts[dst[e]], 1);
}

// per-block exclusive scan of 256 counts; emits block total
__global__ void scan_local_kernel(const int* __restrict__ counts,
                                  int* __restrict__ locscan,
                                  int* __restrict__ blocksums, int N) {
    __shared__ int wsum[4];
    __shared__ int woff[4];
    const int tid = threadIdx.x;
    const int lane = tid & 63;
    const int w = tid >> 6;
    const int i = blockIdx.x * 256 + tid;
    const int x = (i < N) ? counts[i] : 0;
    int ix = x;
    #pragma unroll
    for (int off = 1; off < 64; off <<= 1) {
        int y = __shfl_up(ix, off);
        if (lane >= off) ix += y;
    }
    if (lane == 63) wsum[w] = ix;
    __syncthreads();
    if (tid == 0) {
        int a = 0;
        #pragma unroll
        for (int j = 0; j < 4; ++j) { int t = wsum[j]; woff[j] = a; a += t; }
        blocksums[blockIdx.x] = a;
    }
    __syncthreads();
    if (i < N) locscan[i] = ix - x + woff[w];
}

// single block: exclusive scan of NB block sums (NB<=256 -> 1 chunk); total -> offsets[N]
__global__ void scan_sums_kernel(int* __restrict__ blocksums,
                                 int* __restrict__ offsets, int NB, int N) {
    __shared__ int wsum[4];
    __shared__ int woff[4];
    __shared__ int carry_sh, ctot_sh;
    const int tid = threadIdx.x;
    const int lane = tid & 63;
    const int w = tid >> 6;
    if (tid == 0) carry_sh = 0;
    __syncthreads();
    for (int base = 0; base < NB; base += 256) {
        const int i = base + tid;
        const int x = (i < NB) ? blocksums[i] : 0;
        int ix = x;
        #pragma unroll
        for (int off = 1; off < 64; off <<= 1) {
            int y = __shfl_up(ix, off);
            if (lane >= off) ix += y;
        }
        if (lane == 63) wsum[w] = ix;
        __syncthreads();
        if (tid == 0) {
            int a = 0;
            #pragma unroll
            for (int j = 0; j < 4; ++j) { int t = wsum[j]; woff[j] = a; a += t; }
            ctot_sh = a;
        }
        __syncthreads();
        if (i < NB) blocksums[i] = ix - x + woff[w] + carry_sh;
        __syncthreads();
        if (tid == 0) carry_sh += ctot_sh;
        __syncthreads();
    }
    if (tid == 0) offsets[N] = carry_sh;
}

__global__ void scan_final_kernel(const int* __restrict__ locscan,
                                  const int* __restrict__ blocksums,
                                  int* __restrict__ offsets,
                                  int* __restrict__ cursor, int N) {
    int i = blockIdx.x * 256 + threadIdx.x;
    if (i < N) {
        int o = locscan[i] + blocksums[blockIdx.x];
        offsets[i] = o;
        cursor[i] = o;
    }
}

__global__ void scatter_kernel(const int* __restrict__ dst, int* __restrict__ cursor,
                               int* __restrict__ sorted, int E) {
    int e = blockIdx.x * 256 + threadIdx.x;
    if (e < E) {
        int p = atomicAdd(&cursor[dst[e]], 1);
        sorted[p] = e;
    }
}

// ---------------------------------------------------------------------------
// edge_accum v2. One wave = one (node, feature-half). Changes vs v1 (which
// showed VGPR=64 -> Wr arrays spilled, VALUBusy 78%):
//  - Wr held as 60 NAMED scalar consts (SSA values, no indexable array).
//  - rbf via Chebyshev recurrence: sin((k+1)t) = 2cos(t)sin(kt) - sin((k-1)t),
//    t = pi*d/5 from one __sinf+__cosf. Kills 20 sinf + 20 shfl per edge.
//    fcut = 0.5(cos t + 1) reuses the same c1. 1/d folded into dot epilogue.
// ---------------------------------------------------------------------------
__launch_bounds__(256, 4)
__global__ void edge_accum_kernel(const float* __restrict__ r_ij,
                                  const int* __restrict__ src,
                                  const int* __restrict__ offsets,
                                  const int* __restrict__ sorted,
                                  const float* __restrict__ Wr,
                                  const float* __restrict__ br,
                                  const float* __restrict__ phi,
                                  const float* __restrict__ v,
                                  float* __restrict__ out_v,
                                  float* __restrict__ out_s,
                                  int N) {
    const int tid    = threadIdx.x;
    const int lane   = tid & 63;
    const int wid    = tid >> 6;
    const int witem0 = blockIdx.x * 4 + wid;
    const int istep  = gridDim.x * 4;          // even -> h invariant
    const int h      = witem0 & 1;
    const int f      = h * 64 + lane;

#define LDW(K) const float wA##K = Wr[(K)*384 + f]; \
               const float wB##K = Wr[(K)*384 + 128 + f]; \
               const float wC##K = Wr[(K)*384 + 256 + f];
    LDW(0) LDW(1) LDW(2) LDW(3) LDW(4) LDW(5) LDW(6) LDW(7) LDW(8) LDW(9)
    LDW(10) LDW(11) LDW(12) LDW(13) LDW(14) LDW(15) LDW(16) LDW(17) LDW(18) LDW(19)
#undef LDW
    const float br_a = br[f];
    const float br_b = br[128 + f];
    const float br_c = br[256 + f];

    for (int witem = witem0; witem < 2 * N; witem += istep) {
        const int n   = witem >> 1;
        const int beg = offsets[n];
        const int end = offsets[n + 1];

        float acc_s = 0.f, acc_x = 0.f, acc_y = 0.f, acc_z = 0.f;

        for (int kb = beg; kb < end; kb += 64) {
            const int kk = kb + lane;
            int   sn = 0;
            float rx = 0.f, ry = 0.f, rz = 0.f;
            if (kk < end) {
                const int eid = sorted[kk];
                sn = src[eid];
                rx = r_ij[eid * 3 + 0];
                ry = r_ij[eid * 3 + 1];
                rz = r_ij[eid * 3 + 2];
            }
            const int cnt = min(64, end - kb);
            for (int j = 0; j < cnt; ++j) {
                const int   snj = __shfl(sn, j);
                const float x   = __shfl(rx, j);
                const float y   = __shfl(ry, j);
                const float z   = __shfl(rz, j);

                const size_t sb = (size_t)snj * 384;
                const float pa = phi[sb + f];
                const float pb = phi[sb + 128 + f];
                const float pc = phi[sb + 256 + f];
                const float vx = v[sb + f];
                const float vy = v[sb + 128 + f];
                const float vz = v[sb + 256 + f];

                const float d     = sqrtf(x * x + y * y + z * z);
                const float inv_d = 1.0f / d;
                const float th    = d * (PI_F / RCUT);
                const float s1    = __sinf(th);
                const float c1    = __cosf(th);
                const float fc    = (d < RCUT) ? 0.5f * (c1 + 1.0f) : 0.f;
                const float tc    = 2.0f * c1;

                // Chebyshev recurrence interleaved with the 3 dots
                float sk_1 = 0.f;          // sin(0*t)
                float sk   = s1;           // sin(1*t)
                float dA = sk * wA0, dB = sk * wB0, dC = sk * wC0;
#define STEP(K) { const float s_n = tc * sk - sk_1; sk_1 = sk; sk = s_n; \
                  dA = fmaf(sk, wA##K, dA); dB = fmaf(sk, wB##K, dB); dC = fmaf(sk, wC##K, dC); }
                STEP(1) STEP(2) STEP(3) STEP(4) STEP(5) STEP(6) STEP(7) STEP(8) STEP(9)
                STEP(10) STEP(11) STEP(12) STEP(13) STEP(14) STEP(15) STEP(16) STEP(17) STEP(18) STEP(19)
#undef STEP

                const float wa = fc * fmaf(inv_d, dA, br_a);
                const float wb = fc * fmaf(inv_d, dB, br_b);
                const float wc = fc * fmaf(inv_d, dC, br_c);

                const float a = wa * pa;
                const float b = wb * pb;
                const float c = wc * pc;

                acc_s += b;
                acc_x = fmaf(a, vx, fmaf(c, x * inv_d, acc_x));
                acc_y = fmaf(a, vy, fmaf(c, y * inv_d, acc_y));
                acc_z = fmaf(a, vz, fmaf(c, z * inv_d, acc_z));
            }
        }

        out_s[(size_t)n * 128 + f] = acc_s;
        const size_t ob = (size_t)n * 384;
        out_v[ob + f]        = acc_x;
        out_v[ob + 128 + f]  = acc_y;
        out_v[ob + 256 + f]  = acc_z;
    }
}

// ---------------------------------------------------------------------------
extern "C" void kernel_launch(void* const* d_in, const int* in_sizes, int n_in,
                              void* d_out, int out_size, void* d_ws, size_t ws_size,
                              hipStream_t stream) {
    const float* s    = (const float*)d_in[0];
    const float* v    = (const float*)d_in[1];
    const float* r_ij = (const float*)d_in[2];
    const int*   src  = (const int*)d_in[3];
    const int*   dst  = (const int*)d_in[4];
    const float* W1   = (const float*)d_in[5];
    const float* b1   = (const float*)d_in[6];
    const float* W2   = (const float*)d_in[7];
    const float* b2   = (const float*)d_in[8];
    const float* Wr   = (const float*)d_in[9];
    const float* br   = (const float*)d_in[10];

    const int N = in_sizes[0] / FDIM;   // 50000
    const int E = in_sizes[3];          // 400000
    const int NB = (N + 255) / 256;     // scan blocks (196)

    // ws layout: phi (N*384 f32) | offsets(N+1) | cursor(N) | sorted(E)
    //          | locscan(N) | blocksums(NB)
    float* phi       = (float*)d_ws;
    int*   offsets   = (int*)(phi + (size_t)N * 384);
    int*   cursor    = offsets + (N + 1);        // doubles as counts
    int*   sorted    = cursor + N;
    int*   locscan   = sorted + E;
    int*   blocksums = locscan + N;

    float* out_v = (float*)d_out;                    // N x 3 x 128
    float* out_s = (float*)d_out + (size_t)N * 384;  // N x 128

    hipMemsetAsync(cursor, 0, (size_t)N * sizeof(int), stream);

    hist_kernel<<<dim3((E + 255) / 256), 256, 0, stream>>>(dst, cursor, E);

    dim3 g1((N + 63) / 64);
    node_phi_kernel<<<g1, 256, 0, stream>>>(s, W1, b1, W2, b2, phi, N);

    scan_local_kernel<<<dim3(NB), 256, 0, stream>>>(cursor, locscan, blocksums, N);
    scan_sums_kernel<<<dim3(1), 256, 0, stream>>>(blocksums, offsets, NB, N);
    scan_final_kernel<<<dim3(NB), 256, 0, stream>>>(locscan, blocksums, offsets, cursor, N);

    scatter_kernel<<<dim3((E + 255) / 256), 256, 0, stream>>>(dst, cursor, sorted, E);

    edge_accum_kernel<<<dim3(2048), 256, 0, stream>>>(r_ij, src, offsets, sorted,
                                                      Wr, br, phi, v,
                                                      out_v, out_s, N);
}